// Round 2
// baseline (30.215 us; speedup 1.0000x reference)
//
#include <hip/hip_runtime.h>

#define BLOCK 256
#define EPSF 1e-8f

// LDS plan (aliased regions, 26624 B):
//   phase 1 (staging): float stage[2*2816]   -> box slab [0..2815], tgt slab [2816..5631] (22528 B)
//   phase 2 (clip):    float2 clipA[7*BLOCK] (14336 B) ; float2 clipB[6*BLOCK] (12288 B)
// Threads copy their 12 needed stage values to regs between two __syncthreads,
// then the clip buffers may overwrite the staging region.
#define SMEM_BYTES 26624

__global__ __launch_bounds__(BLOCK) void box_loss_main(
    const float* __restrict__ box, const float* __restrict__ tgt,
    const float* __restrict__ wgt, int n, float* __restrict__ partials)
{
    __shared__ __align__(16) char smem[SMEM_BYTES];
    __shared__ float red[2][BLOCK / 64];

    float*  stage = (float*)smem;                                   // [5632]
    float2* clipA = (float2*)smem;                                  // [7*BLOCK]
    float2* clipB = (float2*)(smem + 7 * BLOCK * sizeof(float2));   // [6*BLOCK]

    const int tid  = threadIdx.x;
    const int slab = blockIdx.x * BLOCK;
    const int slabN = min(BLOCK, n - slab);
    const size_t g0 = (size_t)slab * 11;

    // ---- phase 1: coalesced float4 staging + on-the-fly L1 ----
    float l1sum = 0.f;
    if (slabN == BLOCK) {
        const float4* b4 = (const float4*)(box + g0);
        const float4* t4 = (const float4*)(tgt + g0);
        const float4* w4 = (const float4*)(wgt + g0);
        float4* sb4 = (float4*)stage;            // 704 float4 = 2816 floats
        float4* st4 = (float4*)(stage + 2816);
#pragma unroll
        for (int k = 0; k < 3; ++k) {
            int idx = tid + k * BLOCK;
            if (idx < 704) {
                float4 vb = b4[idx], vt = t4[idx], vw = w4[idx];
                l1sum += fabsf(vb.x - vt.x) * vw.x + fabsf(vb.y - vt.y) * vw.y
                       + fabsf(vb.z - vt.z) * vw.z + fabsf(vb.w - vt.w) * vw.w;
                sb4[idx] = vb;
                st4[idx] = vt;
            }
        }
    } else {
        const int F = slabN * 11;
        for (int j = tid; j < F; j += BLOCK) {
            float bb = box[g0 + j], tt = tgt[g0 + j], ww = wgt[g0 + j];
            l1sum += fabsf(bb - tt) * ww;
            stage[j] = bb; stage[2816 + j] = tt;
        }
    }
    __syncthreads();

    // ---- pull this thread's box params from staged data ----
    float cx1 = 0, cy1 = 0, lw1 = 0, ll1 = 0, sy1 = 0, cyw1 = 0;
    float cx2 = 0, cy2 = 0, lw2 = 0, ll2 = 0, sy2 = 0, cyw2 = 0;
    const bool active = (tid < slabN);
    if (active) {
        const int b = tid * 11;
        cx1 = stage[b + 0]; cy1 = stage[b + 1];
        lw1 = stage[b + 3]; ll1 = stage[b + 4];
        sy1 = stage[b + 6]; cyw1 = stage[b + 7];
        const int t = 2816 + b;
        cx2 = stage[t + 0]; cy2 = stage[t + 1];
        lw2 = stage[t + 3]; ll2 = stage[t + 4];
        sy2 = stage[t + 6]; cyw2 = stage[t + 7];
    }
    __syncthreads();   // staging region now reusable as clip buffers

    float giou_term = 0.f;
    if (active) {
        // decode: sin(atan2(s,c)) = s*rsqrt(s^2+c^2), cos likewise; exp via HW
        float w1 = __expf(lw1), l1 = __expf(ll1);
        float w2 = __expf(lw2), l2 = __expf(ll2);
        float r1 = rsqrtf(fmaxf(sy1 * sy1 + cyw1 * cyw1, 1e-30f));
        float s1 = sy1 * r1, c1 = cyw1 * r1;
        float r2 = rsqrtf(fmaxf(sy2 * sy2 + cyw2 * cyw2, 1e-30f));
        float s2 = sy2 * r2, c2 = cyw2 * r2;

        float hx1 = 0.5f * w1, hy1 = 0.5f * l1;
        float hx2 = 0.5f * w2, hy2 = 0.5f * l2;

        const float LX[4] = { -1.f, 1.f, 1.f, -1.f };
        const float LY[4] = { -1.f, -1.f, 1.f, 1.f };
        float v1x[4], v1y[4], v2x[4], v2y[4];
#pragma unroll
        for (int k = 0; k < 4; ++k) {
            float lx = LX[k] * hx1, ly = LY[k] * hy1;
            v1x[k] = lx * c1 - ly * s1 + cx1;
            v1y[k] = lx * s1 + ly * c1 + cy1;
            float mx = LX[k] * hx2, my = LY[k] * hy2;
            v2x[k] = mx * c2 - my * s2 + cx2;
            v2y[k] = mx * s2 + my * c2 + cy2;
        }

        // enclosing AABB over the 8 original vertices
        float minx = v1x[0], maxx = v1x[0], miny = v1y[0], maxy = v1y[0];
#pragma unroll
        for (int k = 1; k < 4; ++k) {
            minx = fminf(minx, v1x[k]); maxx = fmaxf(maxx, v1x[k]);
            miny = fminf(miny, v1y[k]); maxy = fmaxf(maxy, v1y[k]);
        }
#pragma unroll
        for (int k = 0; k < 4; ++k) {
            minx = fminf(minx, v2x[k]); maxx = fmaxf(maxx, v2x[k]);
            miny = fminf(miny, v2y[k]); maxy = fmaxf(maxy, v2y[k]);
        }
        float enc = (maxx - minx) * (maxy - miny);

        // ---- Sutherland-Hodgman, 4 passes ----
        // pass 0: registers -> clipA (edge v2[0]->v2[1])
        int cnt;
        {
            float ax = v2x[0], ay = v2y[0];
            float dx = v2x[1] - ax, dy = v2y[1] - ay;
            int m = 0;
            float prx = v1x[3], pry = v1y[3];
            bool pin = (dx * (pry - ay) - dy * (prx - ax)) >= 0.f;
#pragma unroll
            for (int ii = 0; ii < 4; ++ii) {
                float cxx = v1x[ii], cyy = v1y[ii];
                bool cin = (dx * (cyy - ay) - dy * (cxx - ax)) >= 0.f;
                if ((cin != pin) && m < 7) {
                    float num = (ax - prx) * dy - (ay - pry) * dx;
                    float den = (cxx - prx) * dy - (cyy - pry) * dx + EPSF;
                    float t = num / den;
                    clipA[m * BLOCK + tid] = make_float2(prx + t * (cxx - prx),
                                                         pry + t * (cyy - pry));
                    ++m;
                }
                if (cin && m < 7) { clipA[m * BLOCK + tid] = make_float2(cxx, cyy); ++m; }
                prx = cxx; pry = cyy; pin = cin;
            }
            cnt = (m < 3) ? 0 : m;
        }

        // generic LDS->LDS pass
        auto clip_lds = [&](const float2* src, int scnt, float2* dst, int cap,
                            float ax, float ay, float dx, float dy) -> int {
            int m = 0;
            float2 pv = src[(scnt - 1) * BLOCK + tid];
            bool pin = (dx * (pv.y - ay) - dy * (pv.x - ax)) >= 0.f;
            for (int ii = 0; ii < scnt; ++ii) {
                float2 cv = src[ii * BLOCK + tid];
                bool cin = (dx * (cv.y - ay) - dy * (cv.x - ax)) >= 0.f;
                if ((cin != pin) && m < cap) {
                    float num = (ax - pv.x) * dy - (ay - pv.y) * dx;
                    float den = (cv.x - pv.x) * dy - (cv.y - pv.y) * dx + EPSF;
                    float t = num / den;
                    dst[m * BLOCK + tid] = make_float2(pv.x + t * (cv.x - pv.x),
                                                       pv.y + t * (cv.y - pv.y));
                    ++m;
                }
                if (cin && m < cap) { dst[m * BLOCK + tid] = cv; ++m; }
                pv = cv; pin = cin;
            }
            return (m < 3) ? 0 : m;
        };

        if (cnt) {   // pass 1: clipA -> clipB (edge v2[1]->v2[2])
            cnt = clip_lds(clipA, cnt, clipB, 6,
                           v2x[1], v2y[1], v2x[2] - v2x[1], v2y[2] - v2y[1]);
        }
        if (cnt) {   // pass 2: clipB -> clipA (edge v2[2]->v2[3])
            cnt = clip_lds(clipB, cnt, clipA, 7,
                           v2x[2], v2y[2], v2x[3] - v2x[2], v2y[3] - v2y[2]);
        }

        // pass 3: clipA -> streaming shoelace (edge v2[3]->v2[0])
        float inter = 0.f;
        if (cnt) {
            float ax = v2x[3], ay = v2y[3];
            float dx = v2x[0] - ax, dy = v2y[0] - ay;
            int m = 0;
            float fx = 0.f, fy = 0.f, lx = 0.f, ly = 0.f, acc = 0.f;
            float2 pv = clipA[(cnt - 1) * BLOCK + tid];
            bool pin = (dx * (pv.y - ay) - dy * (pv.x - ax)) >= 0.f;
            for (int ii = 0; ii < cnt; ++ii) {
                float2 cv = clipA[ii * BLOCK + tid];
                bool cin = (dx * (cv.y - ay) - dy * (cv.x - ax)) >= 0.f;
                if ((cin != pin) && m < 8) {
                    float num = (ax - pv.x) * dy - (ay - pv.y) * dx;
                    float den = (cv.x - pv.x) * dy - (cv.y - pv.y) * dx + EPSF;
                    float t = num / den;
                    float px = pv.x + t * (cv.x - pv.x);
                    float py = pv.y + t * (cv.y - pv.y);
                    if (m == 0) { fx = px; fy = py; }
                    else        { acc += lx * py - ly * px; }
                    lx = px; ly = py; ++m;
                }
                if (cin && m < 8) {
                    if (m == 0) { fx = cv.x; fy = cv.y; }
                    else        { acc += lx * cv.y - ly * cv.x; }
                    lx = cv.x; ly = cv.y; ++m;
                }
                pv = cv; pin = cin;
            }
            if (m >= 3) {
                acc += lx * fy - ly * fx;   // wrap
                inter = fabsf(acc) * 0.5f;
            }
        }

        float areaU = w1 * l1 + w2 * l2 - inter;
        float iou = inter / (areaU + EPSF);
        float giou = iou - (enc - areaU) / (enc + EPSF);
        giou_term = 1.f - giou;
    }

    // ---- block reduction (wave=64) ----
    float sum_box = l1sum, sum_giou = giou_term;
#pragma unroll
    for (int off = 32; off > 0; off >>= 1) {
        sum_box  += __shfl_down(sum_box, off);
        sum_giou += __shfl_down(sum_giou, off);
    }
    const int wave = tid >> 6, lane = tid & 63;
    if (lane == 0) { red[0][wave] = sum_box; red[1][wave] = sum_giou; }
    __syncthreads();
    if (tid == 0) {
        float a = 0.f, g = 0.f;
#pragma unroll
        for (int k = 0; k < BLOCK / 64; ++k) { a += red[0][k]; g += red[1][k]; }
        partials[(size_t)blockIdx.x * 2 + 0] = a;
        partials[(size_t)blockIdx.x * 2 + 1] = g;
    }
}

// Final kernel: deterministic reduction of per-block partials + 1/af scaling.
__global__ __launch_bounds__(256) void box_loss_final(
    const float* __restrict__ partials, int nblk,
    const int* __restrict__ avg_factor, float* __restrict__ out)
{
    __shared__ float red[2][4];
    float a = 0.f, g = 0.f;
    for (int i = threadIdx.x; i < nblk; i += 256) {
        a += partials[(size_t)i * 2 + 0];
        g += partials[(size_t)i * 2 + 1];
    }
#pragma unroll
    for (int off = 32; off > 0; off >>= 1) {
        a += __shfl_down(a, off);
        g += __shfl_down(g, off);
    }
    const int wave = threadIdx.x >> 6, lane = threadIdx.x & 63;
    if (lane == 0) { red[0][wave] = a; red[1][wave] = g; }
    __syncthreads();
    if (threadIdx.x == 0) {
        float af = (float)(*avg_factor);
        if (af < 1.f) af = 1.f;
        float sa = red[0][0] + red[0][1] + red[0][2] + red[0][3];
        float sg = red[1][0] + red[1][1] + red[1][2] + red[1][3];
        out[0] = sa / af;
        out[1] = sg / af;
    }
}

extern "C" void kernel_launch(void* const* d_in, const int* in_sizes, int n_in,
                              void* d_out, int out_size, void* d_ws, size_t ws_size,
                              hipStream_t stream) {
    const float* box = (const float*)d_in[0];
    const float* tgt = (const float*)d_in[1];
    const float* wgt = (const float*)d_in[2];
    const int*   af  = (const int*)d_in[3];
    float* out = (float*)d_out;
    float* partials = (float*)d_ws;

    int n = in_sizes[0] / 11;                 // number of boxes
    int nblk = (n + BLOCK - 1) / BLOCK;       // one box per thread
    if (nblk < 1) nblk = 1;

    hipLaunchKernelGGL(box_loss_main, dim3(nblk), dim3(BLOCK), 0, stream,
                       box, tgt, wgt, n, partials);
    hipLaunchKernelGGL(box_loss_final, dim3(1), dim3(256), 0, stream,
                       partials, nblk, af, out);
}